// Round 6
// baseline (892.753 us; speedup 1.0000x reference)
//
#include <hip/hip_runtime.h>
#include <hip/hip_bf16.h>
#include <math.h>

#define T_TOK 4096
#define D_DIM 1024
#define I_DIM 4096
#define E_EXP 8
#define MAX_TILES 72

typedef __attribute__((ext_vector_type(8))) short bf16x8;
typedef __attribute__((ext_vector_type(4))) float f32x4;

__device__ __forceinline__ unsigned short f2bf(float x) {
    unsigned int u = __float_as_uint(x);
    u += 0x7fffu + ((u >> 16) & 1u);   // RNE
    return (unsigned short)(u >> 16);
}

// async global->LDS, 16B per lane; lds dest = wave-uniform base + lane*16
__device__ __forceinline__ void glds16(const unsigned short* g, unsigned short* l) {
    __builtin_amdgcn_global_load_lds(
        (const __attribute__((address_space(1))) unsigned int*)g,
        (__attribute__((address_space(3))) unsigned int*)(unsigned int)(unsigned long long)(void*)l,
        16, 0, 0);
}

#define VMWAIT6 asm volatile("s_waitcnt vmcnt(6)" ::: "memory")
#define VMWAIT0 asm volatile("s_waitcnt vmcnt(0)" ::: "memory")

__device__ __forceinline__ void bar() {
    asm volatile("" ::: "memory");
    __builtin_amdgcn_s_barrier();
    asm volatile("" ::: "memory");
}

// ---------------- gate + H->bf16: logits (fp32), softmax, top-2, weights, Hbf write -------
__global__ void gate_kernel(const float* __restrict__ h, const float* __restrict__ gw,
                            int* __restrict__ counts, int* __restrict__ sel,
                            float* __restrict__ wgt, unsigned short* __restrict__ Hbf) {
    int t = blockIdx.x;
    int tid = threadIdx.x;
    const int d4 = tid * 4;                       // 256 threads x 4 = 1024 = D_DIM
    const float4 hv = *(const float4*)(h + (size_t)t * D_DIM + d4);
    union { unsigned short u[4]; ushort4 v; } o;
    o.u[0] = f2bf(hv.x); o.u[1] = f2bf(hv.y); o.u[2] = f2bf(hv.z); o.u[3] = f2bf(hv.w);
    *(ushort4*)(Hbf + (size_t)t * D_DIM + d4) = o.v;

    float acc[E_EXP];
#pragma unroll
    for (int e = 0; e < E_EXP; e++) {
        const float4 g = *(const float4*)(gw + e * D_DIM + d4);
        acc[e] = hv.x * g.x + hv.y * g.y + hv.z * g.z + hv.w * g.w;
    }
#pragma unroll
    for (int e = 0; e < E_EXP; e++)
        for (int off = 32; off > 0; off >>= 1) acc[e] += __shfl_down(acc[e], off, 64);
    __shared__ float red[4][E_EXP];
    int wave = tid >> 6, lane = tid & 63;
    if (lane == 0) {
#pragma unroll
        for (int e = 0; e < E_EXP; e++) red[wave][e] = acc[e];
    }
    __syncthreads();
    if (tid == 0) {
        float lg[E_EXP];
#pragma unroll
        for (int e = 0; e < E_EXP; e++) lg[e] = red[0][e] + red[1][e] + red[2][e] + red[3][e];
        float mx = lg[0];
#pragma unroll
        for (int e = 1; e < E_EXP; e++) mx = fmaxf(mx, lg[e]);
        float p[E_EXP];
#pragma unroll
        for (int e = 0; e < E_EXP; e++) p[e] = expf(lg[e] - mx);
        int i0 = 0; float b0 = p[0];
#pragma unroll
        for (int e = 1; e < E_EXP; e++) if (p[e] > b0) { b0 = p[e]; i0 = e; }
        int i1 = -1; float b1v = -1.f;
#pragma unroll
        for (int e = 0; e < E_EXP; e++) if (e != i0 && p[e] > b1v) { b1v = p[e]; i1 = e; }
        float den = b0 + b1v;
        sel[2 * t] = i0; sel[2 * t + 1] = i1;
        wgt[2 * t] = b0 / den; wgt[2 * t + 1] = b1v / den;
        atomicAdd(&counts[i0], 1);
        atomicAdd(&counts[i1], 1);
    }
}

// ---------------- offsets + cursors + aux loss + compacted tile table (BM=128) ----------------
__global__ void offsets_kernel(const int* __restrict__ counts, int* __restrict__ offs,
                               int* __restrict__ cursors, float* __restrict__ aux_out,
                               int* __restrict__ tile_e, int* __restrict__ tile_m,
                               int* __restrict__ ntiles) {
    if (blockIdx.x == 0 && threadIdx.x == 0) {
        int off = 0; float aux = 0.f; int nt = 0;
        for (int e = 0; e < E_EXP; e++) {
            offs[e] = off; off += counts[e]; cursors[e] = 0;
            float u = (float)counts[e] / (float)T_TOK;
            float d = u - 1.0f / (float)E_EXP;
            aux += d * d;
            for (int m0 = 0; m0 < counts[e]; m0 += 128) {
                tile_e[nt] = e; tile_m[nt] = m0; nt++;
            }
        }
        ntiles[0] = nt;
        aux_out[0] = aux / (float)E_EXP;
    }
}

// ---------------- scatter tokens into per-expert segments ----------------
__global__ void scatter_kernel(const int* __restrict__ sel, const float* __restrict__ wgt,
                               const int* __restrict__ offs, int* __restrict__ cursors,
                               int* __restrict__ tok_list, float* __restrict__ tok_w,
                               int* __restrict__ slot_of) {
    int t = blockIdx.x * 256 + threadIdx.x;
    if (t >= T_TOK) return;
#pragma unroll
    for (int k = 0; k < 2; k++) {
        int e = sel[2 * t + k];
        int pos = atomicAdd(&cursors[e], 1);
        int idx = offs[e] + pos;
        tok_list[idx] = t;
        tok_w[idx] = wgt[2 * t + k];
        slot_of[2 * t + k] = idx;
    }
}

// ---------------- fused weight transpose + fp32->bf16 for BOTH w1 and w2 ----------------
__global__ void transpose_cvt2_kernel(const float* __restrict__ w1, const float* __restrict__ w2,
                                      unsigned short* __restrict__ W1t, unsigned short* __restrict__ W2t) {
    __shared__ float tile[64][65];
    const int z = blockIdx.y;
    const bool isW1 = (z < 8);
    const int e = isW1 ? z : z - 8;
    const int R = isW1 ? D_DIM : I_DIM;
    const int C = isW1 ? I_DIM : D_DIM;
    const float* s = (isW1 ? w1 : w2) + (size_t)e * R * C;
    unsigned short* d = (isW1 ? W1t : W2t) + (size_t)e * R * C;
    const int tpc = C >> 6;                       // tiles along C
    const int tr = blockIdx.x / tpc, tc = blockIdx.x % tpc;
    const int r0 = tr * 64, c0 = tc * 64;
    const int tid = threadIdx.x;
    const int rr = tid >> 4;                      // 0..15
    const int c4 = (tid & 15) * 4;                // 0..60
#pragma unroll
    for (int p = 0; p < 4; p++) {
        const float4 v = *(const float4*)(s + (size_t)(r0 + rr + 16 * p) * C + c0 + c4);
        tile[rr + 16 * p][c4]     = v.x;
        tile[rr + 16 * p][c4 + 1] = v.y;
        tile[rr + 16 * p][c4 + 2] = v.z;
        tile[rr + 16 * p][c4 + 3] = v.w;
    }
    __syncthreads();
#pragma unroll
    for (int p = 0; p < 4; p++) {
        const int oc = rr + 16 * p;               // output row (C-dim index)
        union { unsigned short u[4]; ushort4 v; } o;
#pragma unroll
        for (int k2 = 0; k2 < 4; k2++) o.u[k2] = f2bf(tile[c4 + k2][oc]);
        *(ushort4*)(d + (size_t)(c0 + oc) * R + r0 + c4) = o.v;
    }
}

// ---------------- grouped GEMM, 128x128 tile, 4 waves ----------------------------------------
// LDS-BW fix (r5 model: 48KB/K-step through LDS = 20% MfmaUtil ceiling, measured 19%):
// A goes global->register DIRECT (per-lane 16B vectorized gather, rows via tok_list), only B
// is LDS-staged (glds + zero-conflict XOR swizzle). LDS traffic/K-step halves -> 40% ceiling.
// Schedule per step j: [stage B(j+1) after entry barrier] -> vmcnt(6) retires {A(j) regs,
// B(j) lds} (FIFO: queue at entry = A(j)4,B(j)2,A(j+1)4; +B(j+1)2 -> wait 6) -> bar -> bv
// ds_read + MFMA(av for j) -> load A(j+2) into just-freed reg buffer -> bar.
// MODE 0: mid = gelu(gather(Hbf) @ W1t^T + b1)   -> bf16 mid (2T x I)
// MODE 1: slotbuf = tok_w * (mid @ W2t^T + b2)   -> fp32 slotbuf (2T x D)
template <int MODE>
__launch_bounds__(256, 2)
__global__ void moe_gemm_kernel(const unsigned short* __restrict__ Abase,
                                const unsigned short* __restrict__ Bt,
                                const float* __restrict__ bias,
                                const int* __restrict__ counts, const int* __restrict__ offs,
                                const int* __restrict__ tile_e, const int* __restrict__ tile_m,
                                const int* __restrict__ ntiles,
                                const int* __restrict__ tok_list, const float* __restrict__ tok_w,
                                unsigned short* __restrict__ midout, float* __restrict__ slotbuf) {
    constexpr int K  = (MODE == 0) ? D_DIM : I_DIM;
    constexpr int N  = (MODE == 0) ? I_DIM : D_DIM;
    constexpr int NT = K / 32;     // K-tiles of BK=32 (even: 32 or 128)

    __shared__ __align__(16) unsigned short lB[2][128 * 32];

    const int nwg  = gridDim.x * gridDim.y;
    const int flat = blockIdx.y * gridDim.x + blockIdx.x;
    const int q8 = nwg >> 3, r8 = nwg & 7;
    const int xcd = flat & 7, pos = flat >> 3;
    const int id2 = (xcd < r8 ? xcd * (q8 + 1) : r8 * (q8 + 1) + (xcd - r8) * q8) + pos;
    const int tix = id2 / gridDim.y;
    const int nb  = id2 % gridDim.y;
    if (tix >= ntiles[0]) return;

    const int e   = tile_e[tix];
    const int m0  = tile_m[tix];
    const int Ne  = counts[e];
    const int seg = offs[e];
    const int n0  = nb * 128;

    const int tid  = threadIdx.x;
    const int w    = tid >> 6;
    const int lane = tid & 63;
    const int quad = lane >> 4;
    const int l15  = lane & 15;
    const int wm   = (w >> 1) * 64;    // wave row offset
    const int wn   = (w & 1) * 64;     // wave col offset

    // B staging: each glds covers 16 rows x 64B; lane l -> row base+(l>>2), phys slot l&3.
    const int lrow = lane >> 2;
    const int scol = (((lane & 3) ^ ((lane >> 3) & 3)) & 3) * 8;   // pre-swizzled src col (shorts)
    const int rs   = (((quad ^ ((l15 >> 1) & 3)) & 3) * 8);        // read swizzle (shorts)

    // A direct row pointers: fragment i covers rows wm+i*16+l15; 16B per lane at k-seg quad.
    const unsigned short* gAr[4];
#pragma unroll
    for (int i = 0; i < 4; i++) {
        int mrow = m0 + wm + i * 16 + l15;
        int crow = (mrow < Ne) ? mrow : 0;
        size_t rbase;
        if (MODE == 0) rbase = (size_t)tok_list[seg + crow] * K;
        else           rbase = (size_t)(seg + crow) * K;
        gAr[i] = Abase + rbase + quad * 8;
    }

    const unsigned short* Bte = Bt + (size_t)e * N * K;
    const unsigned short* gB0 = Bte + (size_t)(n0 + w * 32 + lrow) * K + scol;
    const unsigned short* gB1 = gB0 + (size_t)16 * K;

    auto STAGE_B = [&](int t) {
        const int b = t & 1;
        const int off = t * 32;
        glds16(gB0 + off, &lB[b][(w * 32) * 32]);
        glds16(gB1 + off, &lB[b][(w * 32 + 16) * 32]);
    };
    auto LOADA = [&](int t, bf16x8* dst) {
#pragma unroll
        for (int i = 0; i < 4; i++)
            dst[i] = *(const bf16x8*)(gAr[i] + (size_t)t * 32);
    };

    f32x4 acc[4][4];
#pragma unroll
    for (int i = 0; i < 4; i++)
#pragma unroll
        for (int j = 0; j < 4; j++) acc[i][j] = (f32x4){0.f, 0.f, 0.f, 0.f};

    bf16x8 avA[4], avB[4];

    auto COMPUTE = [&](int t, const bf16x8* av) {
        const unsigned short* LB = lB[t & 1];
        bf16x8 bv[4];
#pragma unroll
        for (int j = 0; j < 4; j++)
            bv[j] = *(const bf16x8*)&LB[(wn + j * 16 + l15) * 32 + rs];
        __builtin_amdgcn_s_setprio(1);
#pragma unroll
        for (int i = 0; i < 4; i++)
#pragma unroll
            for (int j = 0; j < 4; j++)
                acc[i][j] = __builtin_amdgcn_mfma_f32_16x16x32_bf16(av[i], bv[j], acc[i][j], 0, 0, 0);
        __builtin_amdgcn_s_setprio(0);
    };

    // prologue: queue = B0(2), A0(4), A1(4)
    STAGE_B(0);
    LOADA(0, avA);
    LOADA(1, avB);

    for (int kt = 0; kt < NT; kt += 2) {
        // ---- step kt (avA, lB[0-buf]) ----
        STAGE_B(kt + 1);                       // safe: readers of lB[(kt+1)&1] passed prev barrier
        VMWAIT6;                               // retires A(kt)+B(kt); leaves A(kt+1),B(kt+1)
        bar();
        COMPUTE(kt, avA);
        if (kt + 2 < NT) LOADA(kt + 2, avA);   // reg buffer just freed by COMPUTE
        bar();
        // ---- step kt+1 (avB, lB[1-buf]) ----
        if (kt + 2 < NT) {
            STAGE_B(kt + 2);
            VMWAIT6;                           // retires A(kt+1)+B(kt+1)
        } else {
            VMWAIT0;                           // final: drain everything
        }
        bar();
        COMPUTE(kt + 1, avB);
        if (kt + 3 < NT) LOADA(kt + 3, avB);
        bar();
    }

    // ---- epilogue ----
    const float* be = bias + (size_t)e * N;
#pragma unroll
    for (int i = 0; i < 4; i++) {
        const int mbase = m0 + wm + i * 16 + quad * 4;
#pragma unroll
        for (int j = 0; j < 4; j++) {
            const int n = n0 + wn + j * 16 + l15;
            const float bvl = be[n];
#pragma unroll
            for (int r = 0; r < 4; r++) {
                const int m = mbase + r;
                if (m < Ne) {
                    float v = acc[i][j][r] + bvl;
                    if (MODE == 0) {
                        v = 0.5f * v * (1.0f + erff(v * 0.70710678118654752f));
                        midout[(size_t)(seg + m) * N + n] = f2bf(v);
                    } else {
                        slotbuf[(size_t)(seg + m) * N + n] = tok_w[seg + m] * v;
                    }
                }
            }
        }
    }
}

// ---------------- residual + mask + LayerNorm ----------------
__global__ void ln_kernel(const float* __restrict__ hs, const float* __restrict__ mask,
                          const float* __restrict__ slotbuf, const int* __restrict__ slot_of,
                          const float* __restrict__ gamma, const float* __restrict__ beta,
                          float* __restrict__ outp) {
    int t = blockIdx.x, tid = threadIdx.x;
    int s0 = slot_of[2 * t], s1 = slot_of[2 * t + 1];
    float mk = mask[t];
    const float4* hr = (const float4*)(hs + (size_t)t * D_DIM);
    const float4* p0 = (const float4*)(slotbuf + (size_t)s0 * D_DIM);
    const float4* p1 = (const float4*)(slotbuf + (size_t)s1 * D_DIM);
    float4 hv = hr[tid], a = p0[tid], b = p1[tid];
    float x0 = hv.x + mk * (a.x + b.x);
    float x1 = hv.y + mk * (a.y + b.y);
    float x2 = hv.z + mk * (a.z + b.z);
    float x3 = hv.w + mk * (a.w + b.w);
    float sum = x0 + x1 + x2 + x3;
    float sq = x0 * x0 + x1 * x1 + x2 * x2 + x3 * x3;
    for (int off = 32; off > 0; off >>= 1) {
        sum += __shfl_down(sum, off, 64);
        sq += __shfl_down(sq, off, 64);
    }
    __shared__ float rsum[4], rsq[4];
    __shared__ float mu_s, rstd_s;
    int wave = tid >> 6, lane = tid & 63;
    if (lane == 0) { rsum[wave] = sum; rsq[wave] = sq; }
    __syncthreads();
    if (tid == 0) {
        float s = rsum[0] + rsum[1] + rsum[2] + rsum[3];
        float q = rsq[0] + rsq[1] + rsq[2] + rsq[3];
        float mu = s / (float)D_DIM;
        float var = q / (float)D_DIM - mu * mu;
        mu_s = mu; rstd_s = rsqrtf(var + 1e-5f);
    }
    __syncthreads();
    float mu = mu_s, rstd = rstd_s;
    const float4* g4 = (const float4*)gamma;
    const float4* b4 = (const float4*)beta;
    float4 g = g4[tid], bb = b4[tid];
    float4 o;
    o.x = (x0 - mu) * rstd * g.x + bb.x;
    o.y = (x1 - mu) * rstd * g.y + bb.y;
    o.z = (x2 - mu) * rstd * g.z + bb.z;
    o.w = (x3 - mu) * rstd * g.w + bb.w;
    ((float4*)(outp + (size_t)t * D_DIM))[tid] = o;
}

extern "C" void kernel_launch(void* const* d_in, const int* in_sizes, int n_in,
                              void* d_out, int out_size, void* d_ws, size_t ws_size,
                              hipStream_t stream) {
    const float* hs    = (const float*)d_in[0];
    const float* mask  = (const float*)d_in[1];
    const float* gw    = (const float*)d_in[2];
    const float* w1    = (const float*)d_in[3];
    const float* b1    = (const float*)d_in[4];
    const float* w2    = (const float*)d_in[5];
    const float* b2    = (const float*)d_in[6];
    const float* gamma = (const float*)d_in[7];
    const float* beta  = (const float*)d_in[8];
    float* out = (float*)d_out;

    char* ws = (char*)d_ws;
    int*   counts   = (int*)(ws + 0);
    int*   cursors  = (int*)(ws + 64);
    int*   offs     = (int*)(ws + 128);
    int*   ntiles   = (int*)(ws + 256);
    int*   tile_e   = (int*)(ws + 512);
    int*   tile_m   = (int*)(ws + 1024);
    int*   sel      = (int*)(ws + 4096);
    float* wgt      = (float*)(ws + 4096 + 1 * 32768);
    int*   slot_of  = (int*)(ws + 4096 + 2 * 32768);
    int*   tok_list = (int*)(ws + 4096 + 3 * 32768);
    float* tok_w    = (float*)(ws + 4096 + 4 * 32768);
    unsigned short* Hbf = (unsigned short*)(ws + (1ull << 20));    //  8 MiB
    unsigned short* W1t = (unsigned short*)(ws + (9ull << 20));    // 64 MiB  (E,I,D) bf16
    unsigned short* W2t = (unsigned short*)(ws + (73ull << 20));   // 64 MiB  (E,D,I) bf16
    unsigned short* mid = (unsigned short*)(ws + (137ull << 20));  // 64 MiB  (2T,I) bf16
    float* slotbuf      = (float*)(ws + (201ull << 20));           // 32 MiB  (2T,D) f32

    hipMemsetAsync(counts, 0, 64, stream);
    gate_kernel<<<T_TOK, 256, 0, stream>>>(hs, gw, counts, sel, wgt, Hbf);
    offsets_kernel<<<1, 64, 0, stream>>>(counts, offs, cursors, out + (size_t)T_TOK * D_DIM,
                                         tile_e, tile_m, ntiles);
    scatter_kernel<<<T_TOK / 256, 256, 0, stream>>>(sel, wgt, offs, cursors, tok_list, tok_w, slot_of);
    transpose_cvt2_kernel<<<dim3(1024, 16), 256, 0, stream>>>(w1, w2, W1t, W2t);
    moe_gemm_kernel<0><<<dim3(MAX_TILES, I_DIM / 128), 256, 0, stream>>>(
        Hbf, W1t, b1, counts, offs, tile_e, tile_m, ntiles, tok_list, tok_w, mid, nullptr);
    moe_gemm_kernel<1><<<dim3(MAX_TILES, D_DIM / 128), 256, 0, stream>>>(
        mid, W2t, b2, counts, offs, tile_e, tile_m, ntiles, tok_list, tok_w, nullptr, slotbuf);
    ln_kernel<<<T_TOK, 256, 0, stream>>>(hs, mask, slotbuf, slot_of, gamma, beta, out);
}

// Round 7
// 771.807 us; speedup vs baseline: 1.1567x; 1.1567x over previous
//
#include <hip/hip_runtime.h>
#include <hip/hip_bf16.h>
#include <math.h>

#define T_TOK 4096
#define D_DIM 1024
#define I_DIM 4096
#define E_EXP 8
#define MAX_TILES 72

typedef __attribute__((ext_vector_type(8))) short bf16x8;
typedef __attribute__((ext_vector_type(4))) float f32x4;

__device__ __forceinline__ unsigned short f2bf(float x) {
    unsigned int u = __float_as_uint(x);
    u += 0x7fffu + ((u >> 16) & 1u);   // RNE
    return (unsigned short)(u >> 16);
}

// async global->LDS, 16B per lane; lds dest = wave-uniform base + lane*16
__device__ __forceinline__ void glds16(const unsigned short* g, unsigned short* l) {
    __builtin_amdgcn_global_load_lds(
        (const __attribute__((address_space(1))) unsigned int*)g,
        (__attribute__((address_space(3))) unsigned int*)(unsigned int)(unsigned long long)(void*)l,
        16, 0, 0);
}

#define VMWAIT8 asm volatile("s_waitcnt vmcnt(8)" ::: "memory")
#define VMWAIT4 asm volatile("s_waitcnt vmcnt(4)" ::: "memory")
#define VMWAIT0 asm volatile("s_waitcnt vmcnt(0)" ::: "memory")

__device__ __forceinline__ void bar() {
    asm volatile("" ::: "memory");
    __builtin_amdgcn_s_barrier();
    asm volatile("" ::: "memory");
}

// ---------------- gate + H->bf16: logits (fp32), softmax, top-2, weights, Hbf write -------
__global__ void gate_kernel(const float* __restrict__ h, const float* __restrict__ gw,
                            int* __restrict__ counts, int* __restrict__ sel,
                            float* __restrict__ wgt, unsigned short* __restrict__ Hbf) {
    int t = blockIdx.x;
    int tid = threadIdx.x;
    const int d4 = tid * 4;                       // 256 threads x 4 = 1024 = D_DIM
    const float4 hv = *(const float4*)(h + (size_t)t * D_DIM + d4);
    union { unsigned short u[4]; ushort4 v; } o;
    o.u[0] = f2bf(hv.x); o.u[1] = f2bf(hv.y); o.u[2] = f2bf(hv.z); o.u[3] = f2bf(hv.w);
    *(ushort4*)(Hbf + (size_t)t * D_DIM + d4) = o.v;

    float acc[E_EXP];
#pragma unroll
    for (int e = 0; e < E_EXP; e++) {
        const float4 g = *(const float4*)(gw + e * D_DIM + d4);
        acc[e] = hv.x * g.x + hv.y * g.y + hv.z * g.z + hv.w * g.w;
    }
#pragma unroll
    for (int e = 0; e < E_EXP; e++)
        for (int off = 32; off > 0; off >>= 1) acc[e] += __shfl_down(acc[e], off, 64);
    __shared__ float red[4][E_EXP];
    int wave = tid >> 6, lane = tid & 63;
    if (lane == 0) {
#pragma unroll
        for (int e = 0; e < E_EXP; e++) red[wave][e] = acc[e];
    }
    __syncthreads();
    if (tid == 0) {
        float lg[E_EXP];
#pragma unroll
        for (int e = 0; e < E_EXP; e++) lg[e] = red[0][e] + red[1][e] + red[2][e] + red[3][e];
        float mx = lg[0];
#pragma unroll
        for (int e = 1; e < E_EXP; e++) mx = fmaxf(mx, lg[e]);
        float p[E_EXP];
#pragma unroll
        for (int e = 0; e < E_EXP; e++) p[e] = expf(lg[e] - mx);
        int i0 = 0; float b0 = p[0];
#pragma unroll
        for (int e = 1; e < E_EXP; e++) if (p[e] > b0) { b0 = p[e]; i0 = e; }
        int i1 = -1; float b1v = -1.f;
#pragma unroll
        for (int e = 0; e < E_EXP; e++) if (e != i0 && p[e] > b1v) { b1v = p[e]; i1 = e; }
        float den = b0 + b1v;
        sel[2 * t] = i0; sel[2 * t + 1] = i1;
        wgt[2 * t] = b0 / den; wgt[2 * t + 1] = b1v / den;
        atomicAdd(&counts[i0], 1);
        atomicAdd(&counts[i1], 1);
    }
}

// ---------------- offsets + cursors + aux loss + compacted tile table (BM=128) ----------------
__global__ void offsets_kernel(const int* __restrict__ counts, int* __restrict__ offs,
                               int* __restrict__ cursors, float* __restrict__ aux_out,
                               int* __restrict__ tile_e, int* __restrict__ tile_m,
                               int* __restrict__ ntiles) {
    if (blockIdx.x == 0 && threadIdx.x == 0) {
        int off = 0; float aux = 0.f; int nt = 0;
        for (int e = 0; e < E_EXP; e++) {
            offs[e] = off; off += counts[e]; cursors[e] = 0;
            float u = (float)counts[e] / (float)T_TOK;
            float d = u - 1.0f / (float)E_EXP;
            aux += d * d;
            for (int m0 = 0; m0 < counts[e]; m0 += 128) {
                tile_e[nt] = e; tile_m[nt] = m0; nt++;
            }
        }
        ntiles[0] = nt;
        aux_out[0] = aux / (float)E_EXP;
    }
}

// ---------------- scatter tokens into per-expert segments ----------------
__global__ void scatter_kernel(const int* __restrict__ sel, const float* __restrict__ wgt,
                               const int* __restrict__ offs, int* __restrict__ cursors,
                               int* __restrict__ tok_list, float* __restrict__ tok_w,
                               int* __restrict__ slot_of) {
    int t = blockIdx.x * 256 + threadIdx.x;
    if (t >= T_TOK) return;
#pragma unroll
    for (int k = 0; k < 2; k++) {
        int e = sel[2 * t + k];
        int pos = atomicAdd(&cursors[e], 1);
        int idx = offs[e] + pos;
        tok_list[idx] = t;
        tok_w[idx] = wgt[2 * t + k];
        slot_of[2 * t + k] = idx;
    }
}

// ---------------- fused weight transpose + fp32->bf16 for BOTH w1 and w2 ----------------
__global__ void transpose_cvt2_kernel(const float* __restrict__ w1, const float* __restrict__ w2,
                                      unsigned short* __restrict__ W1t, unsigned short* __restrict__ W2t) {
    __shared__ float tile[64][65];
    const int z = blockIdx.y;
    const bool isW1 = (z < 8);
    const int e = isW1 ? z : z - 8;
    const int R = isW1 ? D_DIM : I_DIM;
    const int C = isW1 ? I_DIM : D_DIM;
    const float* s = (isW1 ? w1 : w2) + (size_t)e * R * C;
    unsigned short* d = (isW1 ? W1t : W2t) + (size_t)e * R * C;
    const int tpc = C >> 6;                       // tiles along C
    const int tr = blockIdx.x / tpc, tc = blockIdx.x % tpc;
    const int r0 = tr * 64, c0 = tc * 64;
    const int tid = threadIdx.x;
    const int rr = tid >> 4;                      // 0..15
    const int c4 = (tid & 15) * 4;                // 0..60
#pragma unroll
    for (int p = 0; p < 4; p++) {
        const float4 v = *(const float4*)(s + (size_t)(r0 + rr + 16 * p) * C + c0 + c4);
        tile[rr + 16 * p][c4]     = v.x;
        tile[rr + 16 * p][c4 + 1] = v.y;
        tile[rr + 16 * p][c4 + 2] = v.z;
        tile[rr + 16 * p][c4 + 3] = v.w;
    }
    __syncthreads();
#pragma unroll
    for (int p = 0; p < 4; p++) {
        const int oc = rr + 16 * p;               // output row (C-dim index)
        union { unsigned short u[4]; ushort4 v; } o;
#pragma unroll
        for (int k2 = 0; k2 < 4; k2++) o.u[k2] = f2bf(tile[c4 + k2][oc]);
        *(ushort4*)(d + (size_t)(c0 + oc) * R + r0 + c4) = o.v;
    }
}

// ---------------- grouped GEMM, 128x128 tile, 4 waves, 4-deep LDS ring, 3 tiles in flight ---
// r5 structure (proven 155us) + deeper pipeline: single barrier per K-step,
//   loop: vmcnt(8) [tile kt landed; kt+1,kt+2 stay in flight] -> bar -> STAGE(kt+3) -> compute(kt)
// Safety: at top-of-step bar all waves consumed buf[kt-1] (MFMA issue implies ds_reads done),
// which is exactly the buffer STAGE(kt+3) overwrites. Zero-conflict XOR swizzle kept (r2).
// MODE 0: mid = gelu(gather(Hbf) @ W1t^T + b1)   -> bf16 mid (2T x I)
// MODE 1: slotbuf = tok_w * (mid @ W2t^T + b2)   -> fp32 slotbuf (2T x D)
template <int MODE>
__launch_bounds__(256, 4)
__global__ void moe_gemm_kernel(const unsigned short* __restrict__ Abase,
                                const unsigned short* __restrict__ Bt,
                                const float* __restrict__ bias,
                                const int* __restrict__ counts, const int* __restrict__ offs,
                                const int* __restrict__ tile_e, const int* __restrict__ tile_m,
                                const int* __restrict__ ntiles,
                                const int* __restrict__ tok_list, const float* __restrict__ tok_w,
                                unsigned short* __restrict__ midout, float* __restrict__ slotbuf) {
    constexpr int K  = (MODE == 0) ? D_DIM : I_DIM;
    constexpr int N  = (MODE == 0) ? I_DIM : D_DIM;
    constexpr int NT = K / 32;     // K-tiles of BK=32 (32 or 128)

    // 4-deep ring: 64 KiB total -> 2 blocks/CU
    __shared__ __align__(16) unsigned short lA[4][128 * 32];
    __shared__ __align__(16) unsigned short lB[4][128 * 32];

    const int nwg  = gridDim.x * gridDim.y;
    const int flat = blockIdx.y * gridDim.x + blockIdx.x;
    const int q8 = nwg >> 3, r8 = nwg & 7;
    const int xcd = flat & 7, pos = flat >> 3;
    const int id2 = (xcd < r8 ? xcd * (q8 + 1) : r8 * (q8 + 1) + (xcd - r8) * q8) + pos;
    const int tix = id2 / gridDim.y;
    const int nb  = id2 % gridDim.y;
    if (tix >= ntiles[0]) return;

    const int e   = tile_e[tix];
    const int m0  = tile_m[tix];
    const int Ne  = counts[e];
    const int seg = offs[e];
    const int n0  = nb * 128;

    const int tid  = threadIdx.x;
    const int w    = tid >> 6;
    const int lane = tid & 63;
    const int quad = lane >> 4;
    const int l15  = lane & 15;
    const int wm   = (w >> 1) * 64;    // wave row offset
    const int wn   = (w & 1) * 64;     // wave col offset

    const int lrow = lane >> 2;
    const int scol = (((lane & 3) ^ ((lane >> 3) & 3)) & 3) * 8;   // pre-swizzled src col (shorts)
    const int rs   = (((quad ^ ((l15 >> 1) & 3)) & 3) * 8);        // read swizzle (shorts)

    const unsigned short *gA0, *gA1;
    {
        int mr0 = m0 + w * 32 + lrow;
        int mr1 = mr0 + 16;
        int c0 = (mr0 < Ne) ? mr0 : 0;
        int c1 = (mr1 < Ne) ? mr1 : 0;
        size_t r0, r1;
        if (MODE == 0) { r0 = (size_t)tok_list[seg + c0] * K; r1 = (size_t)tok_list[seg + c1] * K; }
        else           { r0 = (size_t)(seg + c0) * K;         r1 = (size_t)(seg + c1) * K; }
        gA0 = Abase + r0 + scol;
        gA1 = Abase + r1 + scol;
    }
    const unsigned short* Bte = Bt + (size_t)e * N * K;
    const unsigned short* gB0 = Bte + (size_t)(n0 + w * 32 + lrow) * K + scol;
    const unsigned short* gB1 = gB0 + (size_t)16 * K;

    auto STAGE = [&](int t) {
        const int b = t & 3, off = t * 32;
        glds16(gA0 + off, &lA[b][(w * 32) * 32]);
        glds16(gA1 + off, &lA[b][(w * 32 + 16) * 32]);
        glds16(gB0 + off, &lB[b][(w * 32) * 32]);
        glds16(gB1 + off, &lB[b][(w * 32 + 16) * 32]);
    };

    f32x4 acc[4][4];
#pragma unroll
    for (int i = 0; i < 4; i++)
#pragma unroll
        for (int j = 0; j < 4; j++) acc[i][j] = (f32x4){0.f, 0.f, 0.f, 0.f};

    // prologue: 3 tiles in flight
    STAGE(0); STAGE(1); STAGE(2);

    for (int kt = 0; kt < NT; ++kt) {
        if (kt + 2 < NT)      { VMWAIT8; }   // retire tile kt; kt+1,kt+2 in flight
        else if (kt + 1 < NT) { VMWAIT4; }   // drain phase
        else                  { VMWAIT0; }
        bar();
        if (kt + 3 < NT) STAGE(kt + 3);      // overwrites buf[kt-1], consumed before bar
        const unsigned short* LA = lA[kt & 3];
        const unsigned short* LB = lB[kt & 3];
        bf16x8 av[4], bv[4];
#pragma unroll
        for (int i = 0; i < 4; i++)
            av[i] = *(const bf16x8*)&LA[(wm + i * 16 + l15) * 32 + rs];
#pragma unroll
        for (int j = 0; j < 4; j++)
            bv[j] = *(const bf16x8*)&LB[(wn + j * 16 + l15) * 32 + rs];
        __builtin_amdgcn_s_setprio(1);
#pragma unroll
        for (int i = 0; i < 4; i++)
#pragma unroll
            for (int j = 0; j < 4; j++)
                acc[i][j] = __builtin_amdgcn_mfma_f32_16x16x32_bf16(av[i], bv[j], acc[i][j], 0, 0, 0);
        __builtin_amdgcn_s_setprio(0);
    }

    // ---- epilogue ----
    const float* be = bias + (size_t)e * N;
#pragma unroll
    for (int i = 0; i < 4; i++) {
        const int mbase = m0 + wm + i * 16 + quad * 4;
#pragma unroll
        for (int j = 0; j < 4; j++) {
            const int n = n0 + wn + j * 16 + l15;
            const float bvl = be[n];
#pragma unroll
            for (int r = 0; r < 4; r++) {
                const int m = mbase + r;
                if (m < Ne) {
                    float v = acc[i][j][r] + bvl;
                    if (MODE == 0) {
                        v = 0.5f * v * (1.0f + erff(v * 0.70710678118654752f));
                        midout[(size_t)(seg + m) * N + n] = f2bf(v);
                    } else {
                        slotbuf[(size_t)(seg + m) * N + n] = tok_w[seg + m] * v;
                    }
                }
            }
        }
    }
}

// ---------------- residual + mask + LayerNorm ----------------
__global__ void ln_kernel(const float* __restrict__ hs, const float* __restrict__ mask,
                          const float* __restrict__ slotbuf, const int* __restrict__ slot_of,
                          const float* __restrict__ gamma, const float* __restrict__ beta,
                          float* __restrict__ outp) {
    int t = blockIdx.x, tid = threadIdx.x;
    int s0 = slot_of[2 * t], s1 = slot_of[2 * t + 1];
    float mk = mask[t];
    const float4* hr = (const float4*)(hs + (size_t)t * D_DIM);
    const float4* p0 = (const float4*)(slotbuf + (size_t)s0 * D_DIM);
    const float4* p1 = (const float4*)(slotbuf + (size_t)s1 * D_DIM);
    float4 hv = hr[tid], a = p0[tid], b = p1[tid];
    float x0 = hv.x + mk * (a.x + b.x);
    float x1 = hv.y + mk * (a.y + b.y);
    float x2 = hv.z + mk * (a.z + b.z);
    float x3 = hv.w + mk * (a.w + b.w);
    float sum = x0 + x1 + x2 + x3;
    float sq = x0 * x0 + x1 * x1 + x2 * x2 + x3 * x3;
    for (int off = 32; off > 0; off >>= 1) {
        sum += __shfl_down(sum, off, 64);
        sq += __shfl_down(sq, off, 64);
    }
    __shared__ float rsum[4], rsq[4];
    __shared__ float mu_s, rstd_s;
    int wave = tid >> 6, lane = tid & 63;
    if (lane == 0) { rsum[wave] = sum; rsq[wave] = sq; }
    __syncthreads();
    if (tid == 0) {
        float s = rsum[0] + rsum[1] + rsum[2] + rsum[3];
        float q = rsq[0] + rsq[1] + rsq[2] + rsq[3];
        float mu = s / (float)D_DIM;
        float var = q / (float)D_DIM - mu * mu;
        mu_s = mu; rstd_s = rsqrtf(var + 1e-5f);
    }
    __syncthreads();
    float mu = mu_s, rstd = rstd_s;
    const float4* g4 = (const float4*)gamma;
    const float4* b4 = (const float4*)beta;
    float4 g = g4[tid], bb = b4[tid];
    float4 o;
    o.x = (x0 - mu) * rstd * g.x + bb.x;
    o.y = (x1 - mu) * rstd * g.y + bb.y;
    o.z = (x2 - mu) * rstd * g.z + bb.z;
    o.w = (x3 - mu) * rstd * g.w + bb.w;
    ((float4*)(outp + (size_t)t * D_DIM))[tid] = o;
}

extern "C" void kernel_launch(void* const* d_in, const int* in_sizes, int n_in,
                              void* d_out, int out_size, void* d_ws, size_t ws_size,
                              hipStream_t stream) {
    const float* hs    = (const float*)d_in[0];
    const float* mask  = (const float*)d_in[1];
    const float* gw    = (const float*)d_in[2];
    const float* w1    = (const float*)d_in[3];
    const float* b1    = (const float*)d_in[4];
    const float* w2    = (const float*)d_in[5];
    const float* b2    = (const float*)d_in[6];
    const float* gamma = (const float*)d_in[7];
    const float* beta  = (const float*)d_in[8];
    float* out = (float*)d_out;

    char* ws = (char*)d_ws;
    int*   counts   = (int*)(ws + 0);
    int*   cursors  = (int*)(ws + 64);
    int*   offs     = (int*)(ws + 128);
    int*   ntiles   = (int*)(ws + 256);
    int*   tile_e   = (int*)(ws + 512);
    int*   tile_m   = (int*)(ws + 1024);
    int*   sel      = (int*)(ws + 4096);
    float* wgt      = (float*)(ws + 4096 + 1 * 32768);
    int*   slot_of  = (int*)(ws + 4096 + 2 * 32768);
    int*   tok_list = (int*)(ws + 4096 + 3 * 32768);
    float* tok_w    = (float*)(ws + 4096 + 4 * 32768);
    unsigned short* Hbf = (unsigned short*)(ws + (1ull << 20));    //  8 MiB
    unsigned short* W1t = (unsigned short*)(ws + (9ull << 20));    // 64 MiB  (E,I,D) bf16
    unsigned short* W2t = (unsigned short*)(ws + (73ull << 20));   // 64 MiB  (E,D,I) bf16
    unsigned short* mid = (unsigned short*)(ws + (137ull << 20));  // 64 MiB  (2T,I) bf16
    float* slotbuf      = (float*)(ws + (201ull << 20));           // 32 MiB  (2T,D) f32

    hipMemsetAsync(counts, 0, 64, stream);
    gate_kernel<<<T_TOK, 256, 0, stream>>>(hs, gw, counts, sel, wgt, Hbf);
    offsets_kernel<<<1, 64, 0, stream>>>(counts, offs, cursors, out + (size_t)T_TOK * D_DIM,
                                         tile_e, tile_m, ntiles);
    scatter_kernel<<<T_TOK / 256, 256, 0, stream>>>(sel, wgt, offs, cursors, tok_list, tok_w, slot_of);
    transpose_cvt2_kernel<<<dim3(1024, 16), 256, 0, stream>>>(w1, w2, W1t, W2t);
    moe_gemm_kernel<0><<<dim3(MAX_TILES, I_DIM / 128), 256, 0, stream>>>(
        Hbf, W1t, b1, counts, offs, tile_e, tile_m, ntiles, tok_list, tok_w, mid, nullptr);
    moe_gemm_kernel<1><<<dim3(MAX_TILES, D_DIM / 128), 256, 0, stream>>>(
        mid, W2t, b2, counts, offs, tile_e, tile_m, ntiles, tok_list, tok_w, nullptr, slotbuf);
    ln_kernel<<<T_TOK, 256, 0, stream>>>(hs, mask, slotbuf, slot_of, gamma, beta, out);
}